// Round 1
// baseline (152.055 us; speedup 1.0000x reference)
//
#include <hip/hip_runtime.h>

#define NQ   131072
#define PCNT 2048

#define HIST_BINS 65536
#define HIST_OFF 0
#define CTRL_OFF (HIST_BINS * 4)          /* 262144 */
#define KEYS_OFF (CTRL_OFF + 256)         /* 262400 */
#define REPS_OFF (KEYS_OFF + NQ * 4)      /* 786688, 16B aligned */
#define PART_OFF (REPS_OFF + PCNT * 16)   /* 819456 */

#define NCH 4                 /* rep chunks */
#define RPC (PCNT / NCH)      /* 512 reps per chunk */
#define QPB 1024              /* queries per block in k_main */

// ctrl layout: [0]=B(high bin) [1]=C0 [2]=T [3]=count_less [4]=K2sel
//              [5]=cnt_less_pos [6]=cnt_eq

__device__ __forceinline__ float sumsq_nc(float x, float y, float z) {
#pragma clang fp contract(off)
  return x * x + y * y + z * z;
}

__global__ __launch_bounds__(256) void k_keys(const float* __restrict__ q,
                                              unsigned* __restrict__ keys,
                                              unsigned* __restrict__ hist) {
  int i = blockIdx.x * blockDim.x + threadIdx.x;
  if (i >= NQ) return;
  float x = q[3 * i], y = q[3 * i + 1], z = q[3 * i + 2];
  float s = sumsq_nc(x, y, z);
  float d = sqrtf(s) - 0.5f;
  unsigned k = __float_as_uint(fabsf(d));  // non-negative float: bits monotone
  keys[i] = k;
  atomicAdd(&hist[k >> 16], 1u);
}

__global__ __launch_bounds__(256) void k_scan1(const unsigned* __restrict__ hist,
                                               unsigned* __restrict__ ctrl) {
  __shared__ unsigned part[256];
  __shared__ unsigned bins[256];
  __shared__ unsigned sel_c, sel_cum;
  int t = threadIdx.x;
  unsigned s = 0;
  for (int j = 0; j < 256; ++j) s += hist[t * 256 + j];
  part[t] = s;
  __syncthreads();
  if (t == 0) {
    unsigned cum = 0; int c = 0;
    for (; c < 256; ++c) {
      if (cum + part[c] >= PCNT) break;
      cum += part[c];
    }
    sel_c = (unsigned)c; sel_cum = cum;
  }
  __syncthreads();
  bins[t] = hist[sel_c * 256 + t];
  __syncthreads();
  if (t == 0) {
    unsigned cum = sel_cum; int b = 0;
    for (; b < 256; ++b) {
      if (cum + bins[b] >= PCNT) break;
      cum += bins[b];
    }
    ctrl[0] = sel_c * 256 + (unsigned)b;  // B: high-16 bin containing 2048th
    ctrl[1] = cum;                        // C0: #keys with high16 < B
  }
}

__global__ __launch_bounds__(256) void k_hist2(const unsigned* __restrict__ keys,
                                               const unsigned* __restrict__ ctrl,
                                               unsigned* __restrict__ hist) {
  int i = blockIdx.x * blockDim.x + threadIdx.x;
  if (i >= NQ) return;
  unsigned B = ctrl[0];
  unsigned k = keys[i];
  if ((k >> 16) == B) atomicAdd(&hist[k & 0xFFFFu], 1u);
}

__global__ __launch_bounds__(256) void k_scan2(const unsigned* __restrict__ hist,
                                               unsigned* __restrict__ ctrl) {
  __shared__ unsigned part[256];
  __shared__ unsigned bins[256];
  __shared__ unsigned sel_c, sel_cum;
  int t = threadIdx.x;
  unsigned s = 0;
  for (int j = 0; j < 256; ++j) s += hist[t * 256 + j];
  part[t] = s;
  __syncthreads();
  if (t == 0) {
    unsigned cum = ctrl[1];  // C0
    int c = 0;
    for (; c < 256; ++c) {
      if (cum + part[c] >= PCNT) break;
      cum += part[c];
    }
    sel_c = (unsigned)c; sel_cum = cum;
  }
  __syncthreads();
  bins[t] = hist[sel_c * 256 + t];
  __syncthreads();
  if (t == 0) {
    unsigned cum = sel_cum; int b = 0;
    for (; b < 256; ++b) {
      if (cum + bins[b] >= PCNT) break;
      cum += bins[b];
    }
    unsigned L = sel_c * 256 + (unsigned)b;
    ctrl[2] = (ctrl[0] << 16) | L;  // T threshold key
    ctrl[3] = cum;                  // count_less (#keys < T)
    ctrl[4] = PCNT - cum;           // K2sel (#keys == T to take), >= 1
    ctrl[5] = 0;                    // cnt_less_pos
    ctrl[6] = 0;                    // cnt_eq
  }
}

__global__ __launch_bounds__(256) void k_compact(const float* __restrict__ q,
                                                 const unsigned* __restrict__ keys,
                                                 unsigned* __restrict__ ctrl,
                                                 float4* __restrict__ reps) {
  int i = blockIdx.x * blockDim.x + threadIdx.x;
  if (i >= NQ) return;
  unsigned T = ctrl[2];
  unsigned k = keys[i];
  if (k > T) return;
  int pos = -1;
  if (k < T) {
    pos = (int)atomicAdd(&ctrl[5], 1u);
  } else {
    unsigned e = atomicAdd(&ctrl[6], 1u);
    if (e < ctrl[4]) pos = (int)(ctrl[3] + e);
  }
  if (pos >= 0) {
    float x = q[3 * i], y = q[3 * i + 1], z = q[3 * i + 2];
    float r2 = sumsq_nc(x, y, z);
    reps[pos] = make_float4(x, y, z, r2);
  }
}

// Each block: one rep-chunk (512 reps in LDS) x 1024 queries (4/thread).
// Computes m = min_j (r2_j - 2 q.r_j); partial[chunk][i] = m.
__global__ __launch_bounds__(256) void k_main(const float* __restrict__ q,
                                              const float4* __restrict__ reps,
                                              float* __restrict__ part) {
  __shared__ float4 lds[RPC];
  int chunk = blockIdx.y;
  int qbase = blockIdx.x * QPB;
  int t = threadIdx.x;
  for (int j = t; j < RPC; j += 256) lds[j] = reps[chunk * RPC + j];
  __syncthreads();

  float qx[4], qy[4], qz[4], mn[4];
#pragma unroll
  for (int k = 0; k < 4; ++k) {
    int i = qbase + k * 256 + t;
    qx[k] = -2.0f * q[3 * i];
    qy[k] = -2.0f * q[3 * i + 1];
    qz[k] = -2.0f * q[3 * i + 2];
    mn[k] = 1e30f;
  }
#pragma unroll 4
  for (int j = 0; j < RPC; ++j) {
    float4 r = lds[j];
#pragma unroll
    for (int k = 0; k < 4; ++k) {
      float tt = fmaf(qx[k], r.x, fmaf(qy[k], r.y, fmaf(qz[k], r.z, r.w)));
      mn[k] = fminf(mn[k], tt);
    }
  }
#pragma unroll
  for (int k = 0; k < 4; ++k) {
    int i = qbase + k * 256 + t;
    part[chunk * NQ + i] = mn[k];
  }
}

__global__ __launch_bounds__(256) void k_final(const float* __restrict__ q,
                                               const float* __restrict__ part,
                                               float* __restrict__ out) {
  int i = blockIdx.x * blockDim.x + threadIdx.x;
  if (i >= NQ) return;
  float x = q[3 * i], y = q[3 * i + 1], z = q[3 * i + 2];
  float s = sumsq_nc(x, y, z);
  float d = sqrtf(s) - 0.5f;
  float m = part[i];
#pragma unroll
  for (int c = 1; c < NCH; ++c) m = fminf(m, part[c * NQ + i]);
  float d2 = fmaxf(s + m, 0.0f);              // q2 + min_t, clamped
  float nd = (d2 > 0.0f) ? sqrtf(d2) : 0.0f;  // safe sqrt
  float sg = (d > 0.0f) ? 1.0f : ((d < 0.0f) ? -1.0f : 0.0f);
  out[i] = fminf(nd * sg, d);
}

extern "C" void kernel_launch(void* const* d_in, const int* in_sizes, int n_in,
                              void* d_out, int out_size, void* d_ws, size_t ws_size,
                              hipStream_t stream) {
  const float* q = (const float*)d_in[0];
  float* out = (float*)d_out;
  char* ws = (char*)d_ws;

  unsigned* hist = (unsigned*)(ws + HIST_OFF);
  unsigned* ctrl = (unsigned*)(ws + CTRL_OFF);
  unsigned* keys = (unsigned*)(ws + KEYS_OFF);
  float4* reps   = (float4*)(ws + REPS_OFF);
  float* part    = (float*)(ws + PART_OFF);

  hipMemsetAsync(hist, 0, HIST_BINS * 4, stream);
  k_keys<<<NQ / 256, 256, 0, stream>>>(q, keys, hist);
  k_scan1<<<1, 256, 0, stream>>>(hist, ctrl);
  hipMemsetAsync(hist, 0, HIST_BINS * 4, stream);
  k_hist2<<<NQ / 256, 256, 0, stream>>>(keys, ctrl, hist);
  k_scan2<<<1, 256, 0, stream>>>(hist, ctrl);
  k_compact<<<NQ / 256, 256, 0, stream>>>(q, keys, ctrl, reps);
  k_main<<<dim3(NQ / QPB, NCH), 256, 0, stream>>>(q, reps, part);
  k_final<<<NQ / 256, 256, 0, stream>>>(q, part, out);
}

// Round 2
// 98.910 us; speedup vs baseline: 1.5373x; 1.5373x over previous
//
#include <hip/hip_runtime.h>

#define NQ   131072
#define PCNT 2048
#define NBIN 4096

// ws layout (bytes)
#define HIST_OFF 0                        /* NBIN*4 = 16384 */
#define CTRL_OFF 16384                    /* 64 B   */
#define KEYS_OFF (16384 + 256)            /* NQ*4   */
#define CAND_OFF (KEYS_OFF + NQ * 4)      /* NQ*4   */
#define REPS_OFF (CAND_OFF + NQ * 4)      /* PCNT*16, 16B aligned */

// ctrl: [0]=B1 [1]=C1 [2]=T [3]=CL(count_less) [4]=K2(eq to take)
//       [5]=curL [6]=curE [7]=cand cursor / M

__device__ __forceinline__ float sumsq_nc(float x, float y, float z) {
#pragma clang fp contract(off)
  return x * x + y * y + z * z;
}

// 128 blocks x 256 thr x 4 keys: keys + LDS-aggregated 12-bit histogram
__global__ __launch_bounds__(256) void k_keys(const float* __restrict__ q,
                                              unsigned* __restrict__ keys,
                                              unsigned* __restrict__ hist) {
  __shared__ unsigned h[NBIN];
  int t = threadIdx.x;
  for (int j = t; j < NBIN; j += 256) h[j] = 0;
  __syncthreads();
  int base = blockIdx.x * 256 + t;
#pragma unroll
  for (int l = 0; l < 4; ++l) {
    int i = base + l * 32768;
    float x = q[3 * i], y = q[3 * i + 1], z = q[3 * i + 2];
    float s = sumsq_nc(x, y, z);
    float d = sqrtf(s) - 0.5f;
    unsigned k = __float_as_uint(fabsf(d));  // nonneg float: bits monotone
    keys[i] = k;
    atomicAdd(&h[k >> 20], 1u);
  }
  __syncthreads();
  for (int j = t; j < NBIN; j += 256) {
    unsigned v = h[j];
    if (v) atomicAdd(&hist[j], v);
  }
}

// 1 block: find coarse bin B1 containing the PCNT-th smallest, C1 = #below
__global__ __launch_bounds__(256) void k_scan1(const unsigned* __restrict__ hist,
                                               unsigned* __restrict__ ctrl) {
  __shared__ unsigned part[256];
  int t = threadIdx.x;
  unsigned s = 0;
  for (int j = 0; j < 16; ++j) s += hist[t * 16 + j];
  part[t] = s;
  __syncthreads();
  if (t == 0) {
    unsigned cum = 0; int c = 0;
    for (; c < 256; ++c) { if (cum + part[c] >= PCNT) break; cum += part[c]; }
    unsigned b = c * 16;
    for (;; ++b) { unsigned v = hist[b]; if (cum + v >= PCNT) break; cum += v; }
    ctrl[0] = b; ctrl[1] = cum;
    ctrl[5] = 0; ctrl[6] = 0; ctrl[7] = 0;
  }
}

// 64 blocks x 256 x 8: push keys whose top-12 == B1 into cand (values only)
__global__ __launch_bounds__(256) void k_compact1(const unsigned* __restrict__ keys,
                                                  unsigned* __restrict__ ctrl,
                                                  unsigned* __restrict__ cand) {
  __shared__ unsigned tot, base, cur;
  int t = threadIdx.x;
  if (t == 0) { tot = 0; }
  __syncthreads();
  unsigned B1 = ctrl[0];
  int st = blockIdx.x * 256 + t;
  unsigned kk[8]; unsigned n = 0;
#pragma unroll
  for (int l = 0; l < 8; ++l) { kk[l] = keys[st + l * 16384]; n += ((kk[l] >> 20) == B1); }
  if (n) atomicAdd(&tot, n);
  __syncthreads();
  if (t == 0) { base = atomicAdd(&ctrl[7], tot); cur = 0; }
  __syncthreads();
  int lane = t & 63;
#pragma unroll
  for (int l = 0; l < 8; ++l) {
    bool m = (kk[l] >> 20) == B1;
    unsigned long long mb = __ballot(m);
    unsigned wcnt = __popcll(mb);
    if (wcnt) {
      unsigned lb = 0;
      if (lane == 0) lb = atomicAdd(&cur, wcnt);
      lb = __shfl(lb, 0);
      if (m) cand[base + lb + __popcll(mb & ((1ull << lane) - 1ull))] = kk[l];
    }
  }
}

// 1 block: exact 32-bit threshold among candidates (bits 19..8 then 7..0)
__global__ __launch_bounds__(256) void k_select(const unsigned* __restrict__ cand,
                                                unsigned* __restrict__ ctrl) {
  __shared__ unsigned h2[NBIN];
  __shared__ unsigned h3[256];
  __shared__ unsigned part[256];
  __shared__ unsigned sB2, sC2, sNeed2;
  int t = threadIdx.x;
  unsigned B1 = ctrl[0], C1 = ctrl[1], M = ctrl[7];
  unsigned need = PCNT - C1;
  for (int j = t; j < NBIN; j += 256) h2[j] = 0;
  h3[t] = 0;
  __syncthreads();
  for (unsigned j = t; j < M; j += 256) atomicAdd(&h2[(cand[j] >> 8) & 0xFFFu], 1u);
  __syncthreads();
  unsigned s = 0;
  for (int j = 0; j < 16; ++j) s += h2[t * 16 + j];
  part[t] = s;
  __syncthreads();
  if (t == 0) {
    unsigned cum = 0; int c = 0;
    for (; c < 256; ++c) { if (cum + part[c] >= need) break; cum += part[c]; }
    unsigned b = c * 16;
    for (;; ++b) { unsigned v = h2[b]; if (cum + v >= need) break; cum += v; }
    sB2 = b; sC2 = cum; sNeed2 = need - cum;
  }
  __syncthreads();
  unsigned b2 = sB2;
  for (unsigned j = t; j < M; j += 256) {
    unsigned k = cand[j];
    if (((k >> 8) & 0xFFFu) == b2) atomicAdd(&h3[k & 0xFFu], 1u);
  }
  __syncthreads();
  if (t == 0) {
    unsigned need2 = sNeed2, cum = 0, b = 0;
    for (;; ++b) { unsigned v = h3[b]; if (cum + v >= need2) break; cum += v; }
    unsigned T = (B1 << 20) | (b2 << 8) | b;
    unsigned CL = C1 + sC2 + cum;
    ctrl[2] = T; ctrl[3] = CL; ctrl[4] = PCNT - CL;
  }
}

// 64 blocks x 256 x 8: build reps[] = (x,y,z,r2) for keys<T plus K2 of ==T
__global__ __launch_bounds__(256) void k_repbuild(const float* __restrict__ q,
                                                  const unsigned* __restrict__ keys,
                                                  unsigned* __restrict__ ctrl,
                                                  float4* __restrict__ reps) {
  __shared__ unsigned totL, totE, curL, curE;
  int t = threadIdx.x;
  if (t == 0) { totL = 0; totE = 0; }
  __syncthreads();
  unsigned T = ctrl[2], CL = ctrl[3], K2 = ctrl[4];
  int st = blockIdx.x * 256 + t;
  unsigned kk[8]; unsigned nl = 0, ne = 0;
#pragma unroll
  for (int l = 0; l < 8; ++l) {
    kk[l] = keys[st + l * 16384];
    nl += (kk[l] < T); ne += (kk[l] == T);
  }
  if (nl) atomicAdd(&totL, nl);
  if (ne) atomicAdd(&totE, ne);
  __syncthreads();
  if (t == 0) { curL = atomicAdd(&ctrl[5], totL); curE = atomicAdd(&ctrl[6], totE); }
  __syncthreads();
  int lane = t & 63;
#pragma unroll
  for (int l = 0; l < 8; ++l) {
    int i = st + l * 16384;
    unsigned k = kk[l];
    bool lt = k < T, eq = k == T;
    unsigned long long ml = __ballot(lt), me = __ballot(eq);
    unsigned wl = __popcll(ml), we = __popcll(me);
    unsigned bl = 0, be = 0;
    if (wl) { if (lane == 0) bl = atomicAdd(&curL, wl); bl = __shfl(bl, 0); }
    if (we) { if (lane == 0) be = atomicAdd(&curE, we); be = __shfl(be, 0); }
    int pos = -1;
    if (lt) pos = (int)(bl + __popcll(ml & ((1ull << lane) - 1ull)));
    else if (eq) {
      unsigned e = be + __popcll(me & ((1ull << lane) - 1ull));
      if (e < K2) pos = (int)(CL + e);
    }
    if (pos >= 0) {
      float x = q[3 * i], y = q[3 * i + 1], z = q[3 * i + 2];
      reps[pos] = make_float4(x, y, z, sumsq_nc(x, y, z));
    }
  }
}

// 512 blocks x 256: each thread one query; reps read uniform (scalar loads)
__global__ __launch_bounds__(256) void k_main(const float* __restrict__ q,
                                              const float4* __restrict__ reps,
                                              float* __restrict__ out) {
  int i = blockIdx.x * 256 + threadIdx.x;
  float x = q[3 * i], y = q[3 * i + 1], z = q[3 * i + 2];
  float s = sumsq_nc(x, y, z);
  float d = sqrtf(s) - 0.5f;
  float qx = -2.0f * x, qy = -2.0f * y, qz = -2.0f * z;
  float m0 = 1e30f, m1 = 1e30f, m2 = 1e30f, m3 = 1e30f;
#pragma unroll 4
  for (int j = 0; j < PCNT; j += 4) {
    float4 r0 = reps[j], r1 = reps[j + 1], r2 = reps[j + 2], r3 = reps[j + 3];
    m0 = fminf(m0, fmaf(qx, r0.x, fmaf(qy, r0.y, fmaf(qz, r0.z, r0.w))));
    m1 = fminf(m1, fmaf(qx, r1.x, fmaf(qy, r1.y, fmaf(qz, r1.z, r1.w))));
    m2 = fminf(m2, fmaf(qx, r2.x, fmaf(qy, r2.y, fmaf(qz, r2.z, r2.w))));
    m3 = fminf(m3, fmaf(qx, r3.x, fmaf(qy, r3.y, fmaf(qz, r3.z, r3.w))));
  }
  float m = fminf(fminf(m0, m1), fminf(m2, m3));
  float d2 = fmaxf(s + m, 0.0f);
  float nd = (d2 > 0.0f) ? sqrtf(d2) : 0.0f;
  float sg = (d > 0.0f) ? 1.0f : ((d < 0.0f) ? -1.0f : 0.0f);
  out[i] = fminf(nd * sg, d);
}

extern "C" void kernel_launch(void* const* d_in, const int* in_sizes, int n_in,
                              void* d_out, int out_size, void* d_ws, size_t ws_size,
                              hipStream_t stream) {
  const float* q = (const float*)d_in[0];
  float* out = (float*)d_out;
  char* ws = (char*)d_ws;

  unsigned* hist = (unsigned*)(ws + HIST_OFF);
  unsigned* ctrl = (unsigned*)(ws + CTRL_OFF);
  unsigned* keys = (unsigned*)(ws + KEYS_OFF);
  unsigned* cand = (unsigned*)(ws + CAND_OFF);
  float4* reps   = (float4*)(ws + REPS_OFF);

  hipMemsetAsync(hist, 0, NBIN * 4, stream);
  k_keys<<<128, 256, 0, stream>>>(q, keys, hist);
  k_scan1<<<1, 256, 0, stream>>>(hist, ctrl);
  k_compact1<<<64, 256, 0, stream>>>(keys, ctrl, cand);
  k_select<<<1, 256, 0, stream>>>(cand, ctrl);
  k_repbuild<<<64, 256, 0, stream>>>(q, keys, ctrl, reps);
  k_main<<<NQ / 256, 256, 0, stream>>>(q, reps, out);
}

// Round 3
// 74.588 us; speedup vs baseline: 2.0386x; 1.3261x over previous
//
#include <hip/hip_runtime.h>

#define NQ   131072
#define PCNT 2048
#define NBIN 4096
#define NCH  2
#define RPC  (PCNT / NCH)   /* 1024 reps per chunk */

// ws layout (bytes)
#define HIST_OFF 0                         /* NBIN*4 = 16384 */
#define CTRL_OFF 16384                     /* 256 B  */
#define KEYS_OFF (16384 + 256)             /* NQ*4   */
#define CAND_OFF (KEYS_OFF + NQ * 4)       /* NQ*4   */
#define REPS_OFF (CAND_OFF + NQ * 4)       /* PCNT*16, 16B aligned */
#define PART_OFF (REPS_OFF + PCNT * 16)    /* NCH*NQ*4 */

// ctrl: [5]=curL [6]=curE [7]=cand cursor (M)

__device__ __forceinline__ float sumsq_nc(float x, float y, float z) {
#pragma clang fp contract(off)
  return x * x + y * y + z * z;
}

// 128 blocks x 256 thr x 4 pts: keys + LDS-aggregated 12-bit histogram
__global__ __launch_bounds__(256) void k_keys(const float* __restrict__ q,
                                              unsigned* __restrict__ keys,
                                              unsigned* __restrict__ hist,
                                              unsigned* __restrict__ ctrl) {
  __shared__ unsigned h[NBIN];
  int t = threadIdx.x;
  for (int j = t; j < NBIN; j += 256) h[j] = 0;
  if (blockIdx.x == 0 && t >= 5 && t < 8) ctrl[t] = 0;
  __syncthreads();
  int base = blockIdx.x * 256 + t;
#pragma unroll
  for (int l = 0; l < 4; ++l) {
    int i = base + l * 32768;
    float x = q[3 * i], y = q[3 * i + 1], z = q[3 * i + 2];
    float s = sumsq_nc(x, y, z);
    float d = sqrtf(s) - 0.5f;
    unsigned k = __float_as_uint(fabsf(d));  // nonneg float: bits monotone
    keys[i] = k;
    atomicAdd(&h[k >> 20], 1u);
  }
  __syncthreads();
  for (int j = t; j < NBIN; j += 256) {
    unsigned v = h[j];
    if (v) atomicAdd(&hist[j], v);
  }
}

// per-block coarse scan: bin B1 containing the PCNT-th smallest, C1 = #below
__device__ __forceinline__ void coarse_scan(const unsigned* __restrict__ hist,
                                            unsigned* part, unsigned* pB1,
                                            unsigned* pC1) {
  int t = threadIdx.x;
  unsigned s = 0;
  for (int j = 0; j < 16; ++j) s += hist[t * 16 + j];
  part[t] = s;
  __syncthreads();
  if (t == 0) {
    unsigned cum = 0; int c = 0;
    for (; c < 256; ++c) { if (cum + part[c] >= PCNT) break; cum += part[c]; }
    unsigned b = c * 16;
    for (;; ++b) { unsigned v = hist[b]; if (cum + v >= PCNT) break; cum += v; }
    *pB1 = b; *pC1 = cum;
  }
  __syncthreads();
}

// 64 blocks x 256 x 8: push keys with top-12 == B1 into cand (values only)
__global__ __launch_bounds__(256) void k_compact1(const unsigned* __restrict__ keys,
                                                  const unsigned* __restrict__ hist,
                                                  unsigned* __restrict__ ctrl,
                                                  unsigned* __restrict__ cand) {
  __shared__ unsigned part[256];
  __shared__ unsigned sB1, sC1;
  __shared__ unsigned tot, base, cur;
  int t = threadIdx.x;
  if (t == 0) tot = 0;
  coarse_scan(hist, part, &sB1, &sC1);
  unsigned B1 = sB1;
  int st = blockIdx.x * 256 + t;
  unsigned kk[8]; unsigned n = 0;
#pragma unroll
  for (int l = 0; l < 8; ++l) { kk[l] = keys[st + l * 16384]; n += ((kk[l] >> 20) == B1); }
  if (n) atomicAdd(&tot, n);
  __syncthreads();
  if (t == 0) { base = atomicAdd(&ctrl[7], tot); cur = 0; }
  __syncthreads();
  int lane = t & 63;
#pragma unroll
  for (int l = 0; l < 8; ++l) {
    bool m = (kk[l] >> 20) == B1;
    unsigned long long mb = __ballot(m);
    unsigned wcnt = __popcll(mb);
    if (wcnt) {
      unsigned lb = 0;
      if (lane == 0) lb = atomicAdd(&cur, wcnt);
      lb = __shfl(lb, 0);
      if (m) cand[base + lb + __popcll(mb & ((1ull << lane) - 1ull))] = kk[l];
    }
  }
}

// 64 blocks x 256 x 8: inline exact select (over cand) + build reps[]
__global__ __launch_bounds__(256) void k_repbuild(const float* __restrict__ q,
                                                  const unsigned* __restrict__ keys,
                                                  const unsigned* __restrict__ hist,
                                                  unsigned* __restrict__ ctrl,
                                                  const unsigned* __restrict__ cand,
                                                  float4* __restrict__ reps) {
  __shared__ unsigned part[256];
  __shared__ unsigned h2[NBIN];
  __shared__ unsigned h3[256];
  __shared__ unsigned sB1, sC1, sB2, sC2, sN2, sT, sCL, sK2;
  __shared__ unsigned totL, totE, curL, curE;
  int t = threadIdx.x;
  for (int j = t; j < NBIN; j += 256) h2[j] = 0;
  h3[t] = 0;
  if (t == 0) { totL = 0; totE = 0; }
  coarse_scan(hist, part, &sB1, &sC1);   // includes syncthreads
  unsigned M = ctrl[7];
  for (unsigned j = t; j < M; j += 256) atomicAdd(&h2[(cand[j] >> 8) & 0xFFFu], 1u);
  __syncthreads();
  unsigned s = 0;
  for (int j = 0; j < 16; ++j) s += h2[t * 16 + j];
  part[t] = s;
  __syncthreads();
  if (t == 0) {
    unsigned need = PCNT - sC1;
    unsigned cum = 0; int c = 0;
    for (; c < 256; ++c) { if (cum + part[c] >= need) break; cum += part[c]; }
    unsigned b = c * 16;
    for (;; ++b) { unsigned v = h2[b]; if (cum + v >= need) break; cum += v; }
    sB2 = b; sC2 = cum; sN2 = need - cum;
  }
  __syncthreads();
  unsigned b2 = sB2;
  for (unsigned j = t; j < M; j += 256) {
    unsigned k = cand[j];
    if (((k >> 8) & 0xFFFu) == b2) atomicAdd(&h3[k & 0xFFu], 1u);
  }
  __syncthreads();
  if (t == 0) {
    unsigned need2 = sN2, cum = 0, b = 0;
    for (;; ++b) { unsigned v = h3[b]; if (cum + v >= need2) break; cum += v; }
    sT = (sB1 << 20) | (b2 << 8) | b;
    sCL = sC1 + sC2 + cum;
    sK2 = PCNT - sCL;
  }
  __syncthreads();
  unsigned T = sT, CL = sCL, K2 = sK2;
  int st = blockIdx.x * 256 + t;
  unsigned kk[8]; unsigned nl = 0, ne = 0;
#pragma unroll
  for (int l = 0; l < 8; ++l) {
    kk[l] = keys[st + l * 16384];
    nl += (kk[l] < T); ne += (kk[l] == T);
  }
  if (nl) atomicAdd(&totL, nl);
  if (ne) atomicAdd(&totE, ne);
  __syncthreads();
  if (t == 0) { curL = atomicAdd(&ctrl[5], totL); curE = atomicAdd(&ctrl[6], totE); }
  __syncthreads();
  int lane = t & 63;
#pragma unroll
  for (int l = 0; l < 8; ++l) {
    int i = st + l * 16384;
    unsigned k = kk[l];
    bool lt = k < T, eq = k == T;
    unsigned long long ml = __ballot(lt), me = __ballot(eq);
    unsigned wl = __popcll(ml), we = __popcll(me);
    unsigned bl = 0, be = 0;
    if (wl) { if (lane == 0) bl = atomicAdd(&curL, wl); bl = __shfl(bl, 0); }
    if (we) { if (lane == 0) be = atomicAdd(&curE, we); be = __shfl(be, 0); }
    int pos = -1;
    if (lt) pos = (int)(bl + __popcll(ml & ((1ull << lane) - 1ull)));
    else if (eq) {
      unsigned e = be + __popcll(me & ((1ull << lane) - 1ull));
      if (e < K2) pos = (int)(CL + e);
    }
    if (pos >= 0) {
      float x = q[3 * i], y = q[3 * i + 1], z = q[3 * i + 2];
      reps[pos] = make_float4(x, y, z, sumsq_nc(x, y, z));
    }
  }
}

// grid (512, NCH) x 256: per-thread one query, VMEM (laundered) rep loads
__global__ __launch_bounds__(256) void k_main(const float* __restrict__ q,
                                              const float4* __restrict__ reps,
                                              float* __restrict__ part) {
  int i = blockIdx.x * 256 + threadIdx.x;
  int c = blockIdx.y;
  // Launder a zero through ds_bpermute: compiler can't prove it uniform, so
  // rep loads stay VMEM (global_load_dwordx4, in-order, partial vmcnt waits)
  // instead of being scalarized to s_load (out-of-order -> lgkmcnt(0) drains).
  int joff = __shfl(0, 0);
  const float4* rp = reps + c * RPC + joff;
  float x = q[3 * i], y = q[3 * i + 1], z = q[3 * i + 2];
  float qx = -2.0f * x, qy = -2.0f * y, qz = -2.0f * z;
  float m0 = 1e30f, m1 = 1e30f, m2 = 1e30f, m3 = 1e30f;
#pragma unroll 4
  for (int j = 0; j < RPC; j += 4) {
    float4 r0 = rp[j], r1 = rp[j + 1], r2 = rp[j + 2], r3 = rp[j + 3];
    m0 = fminf(m0, fmaf(qx, r0.x, fmaf(qy, r0.y, fmaf(qz, r0.z, r0.w))));
    m1 = fminf(m1, fmaf(qx, r1.x, fmaf(qy, r1.y, fmaf(qz, r1.z, r1.w))));
    m2 = fminf(m2, fmaf(qx, r2.x, fmaf(qy, r2.y, fmaf(qz, r2.z, r2.w))));
    m3 = fminf(m3, fmaf(qx, r3.x, fmaf(qy, r3.y, fmaf(qz, r3.z, r3.w))));
  }
  part[c * NQ + i] = fminf(fminf(m0, m1), fminf(m2, m3));
}

// 512 blocks: combine chunks + epilogue
__global__ __launch_bounds__(256) void k_reduce(const float* __restrict__ q,
                                                const float* __restrict__ part,
                                                float* __restrict__ out) {
  int i = blockIdx.x * 256 + threadIdx.x;
  float m = fminf(part[i], part[NQ + i]);
  float x = q[3 * i], y = q[3 * i + 1], z = q[3 * i + 2];
  float s = sumsq_nc(x, y, z);
  float d = sqrtf(s) - 0.5f;
  float d2 = fmaxf(s + m, 0.0f);
  float nd = (d2 > 0.0f) ? sqrtf(d2) : 0.0f;
  float sg = (d > 0.0f) ? 1.0f : ((d < 0.0f) ? -1.0f : 0.0f);
  out[i] = fminf(nd * sg, d);
}

extern "C" void kernel_launch(void* const* d_in, const int* in_sizes, int n_in,
                              void* d_out, int out_size, void* d_ws, size_t ws_size,
                              hipStream_t stream) {
  const float* q = (const float*)d_in[0];
  float* out = (float*)d_out;
  char* ws = (char*)d_ws;

  unsigned* hist = (unsigned*)(ws + HIST_OFF);
  unsigned* ctrl = (unsigned*)(ws + CTRL_OFF);
  unsigned* keys = (unsigned*)(ws + KEYS_OFF);
  unsigned* cand = (unsigned*)(ws + CAND_OFF);
  float4* reps   = (float4*)(ws + REPS_OFF);
  float* part    = (float*)(ws + PART_OFF);

  hipMemsetAsync(hist, 0, NBIN * 4, stream);
  k_keys<<<128, 256, 0, stream>>>(q, keys, hist, ctrl);
  k_compact1<<<64, 256, 0, stream>>>(keys, hist, ctrl, cand);
  k_repbuild<<<64, 256, 0, stream>>>(q, keys, hist, ctrl, cand, reps);
  k_main<<<dim3(NQ / 256, NCH), 256, 0, stream>>>(q, reps, part);
  k_reduce<<<NQ / 256, 256, 0, stream>>>(q, part, out);
}